// Round 11
// baseline (230.630 us; speedup 1.0000x reference)
//
#include <hip/hip_runtime.h>
#include <stdint.h>

#define CCH 64
#define KK 27
#define NSL 28                   // 27 conv slices + 1 affine slice
#define WPERM_B (NSL * 4 * 1024) // 114688 B per layer (permuted weights)
#define TV 32                    // voxels per tile
#define OFFN (TV * KK)           // 864 offset entries per tile

typedef int v4i  __attribute__((ext_vector_type(4)));
typedef int v16i __attribute__((ext_vector_type(16)));

// ---------------- prep: permuted weights + affine rows + requant + zero rows ----
// exact: (x*mul)>>31 == mulhi(x, mul<<1); (x*slope)>>25 == mulhi(x, slope<<7)
__global__ void __launch_bounds__(256) k_prep(
    const int* __restrict__ x32, const int* __restrict__ mul0p,
    const int* __restrict__ w1_32, const int* __restrict__ w2_32,
    const int* __restrict__ comp1, const int* __restrict__ b1,
    const int* __restrict__ comp2, const int* __restrict__ b2,
    const int* __restrict__ mask,
    int8_t* __restrict__ w1p, int8_t* __restrict__ w2p,
    int* __restrict__ q0, int* __restrict__ q1, int8_t* __restrict__ af,
    int pb_w, int pb_af, int nvox, int total4)
{
    const int bid = blockIdx.x;
    if (bid < pb_w) {
        const int gtid = bid * 256 + threadIdx.x;
        if (gtid < 2 * WPERM_B) {
            // wperm[((s*2+cinH)*2+coutH)*1024 + l*16 + j]
            //   = w[s][coutH*32+(l&31)][cinH*32+(l>>5)*16+j]   (s<27)
            //   = affine_B[c=cin][cout]                        (s==27)
            const int which = gtid >= WPERM_B;
            const int u = which ? gtid - WPERM_B : gtid;
            const int frag = u >> 10;          // 0..111
            const int l    = (u >> 4) & 63;
            const int j    = u & 15;
            const int s     = frag >> 2;
            const int cinH  = (frag >> 1) & 1;
            const int coutH = frag & 1;
            const int cout = coutH * 32 + (l & 31);
            const int cin  = cinH * 32 + (l >> 5) * 16 + j;
            int v;
            if (s < KK) {
                const int* w = which ? w2_32 : w1_32;
                v = w[((size_t)(s * CCH + cout)) * CCH + cin];
            } else {
                const int* comp = which ? comp2 : comp1;
                const int* bias = which ? b2 : b1;
                const int c = cin;   // encoding channel 0..63
                if (c < 27)       v = comp[c * CCH + cout] >> 2;        // pairs A=4*mask
                else if (c < 54)  v = comp[(c - 27) * CCH + cout] & 3;  // pairs A=1*mask
                else if (c == 54) v = bias[cout] >> 6;                  // pairs A=64
                else if (c == 55) v = bias[cout] & 63;                  // pairs A=1
                else              v = 0;
            }
            (which ? w2p : w1p)[u] = (int8_t)v;
        } else {
            const int u = gtid - 2 * WPERM_B;   // zero rows (row nvox of q0,q1)
            if (u < 16)      q0[(size_t)nvox * 16 + u] = 0;
            else if (u < 32) q1[(size_t)nvox * 16 + (u - 16)] = 0;
        }
    } else if (bid < pb_w + pb_af) {
        // affine A-rows: af[vox][c] = c<27?4m : c<54?m : c==54?64 : c==55?1 : 0
        const int vox = (bid - pb_w) * 256 + threadIdx.x;
        if (vox < nvox) {
            int m[27];
#pragma unroll
            for (int k = 0; k < 27; ++k)
                m[k] = mask[(size_t)vox * 27 + k] ? 1 : 0;
            v4i d[4];
#pragma unroll
            for (int di = 0; di < 16; ++di) {
                int pk = 0;
#pragma unroll
                for (int b = 0; b < 4; ++b) {
                    const int ch = di * 4 + b;
                    int bv = 0;
                    if (ch < 27)       bv = m[ch] << 2;
                    else if (ch < 54)  bv = m[ch - 27];
                    else if (ch == 54) bv = 64;
                    else if (ch == 55) bv = 1;
                    pk |= bv << (8 * b);
                }
                d[di >> 2][di & 3] = pk;
            }
            v4i* dst = (v4i*)(af + (size_t)vox * 64);
            dst[0] = d[0]; dst[1] = d[1]; dst[2] = d[2]; dst[3] = d[3];
        }
    } else {
        const int i = (bid - pb_w - pb_af) * 256 + threadIdx.x;
        if (i < total4) {
            const int mul2 = (*mul0p) << 1;
            const int4 v = ((const int4*)x32)[i];
            int r = 0, q;
            q = __mulhi(v.x, mul2); q = q > 127 ? 127 : (q < -127 ? -127 : q); r |= (q & 0xff);
            q = __mulhi(v.y, mul2); q = q > 127 ? 127 : (q < -127 ? -127 : q); r |= (q & 0xff) << 8;
            q = __mulhi(v.z, mul2); q = q > 127 ? 127 : (q < -127 ? -127 : q); r |= (q & 0xff) << 16;
            q = __mulhi(v.w, mul2); q = q > 127 ? 127 : (q < -127 ? -127 : q); r |= (q & 0xff) << 24;
            q0[i] = r;
        }
    }
}

// Wave-independent 32-voxel-tile conv via mfma_i32_32x32x32_i8, B from LDS.
//  - block = 256 thr = 4 waves, 1 block/CU (LDS 139 KB); NO barriers in loop
//  - weights (permuted, incl. affine slice) loaded once into LDS; B-reads are
//    lane-linear ds_read_b128 (conflict-free)
//  - wave owns whole tiles: A gathered to VGPRs (54 frags), per-wave s_off dbuf
//  - A/B lane maps: row/col = lane&31, k = (lane>>5)*16+j (consistent A/B);
//    C/D: row=(reg&3)+8*(reg>>2)+4*(lane>>5), col=lane&31 (m74-verified)
// REQUIRES nvox % 32 == 0 (100000 = 3125*32).
template <int LAYER>
__global__ void __launch_bounds__(256, 1)
k_conv(const int8_t* __restrict__ fin,   // [(nvox+1)*64] int8 (row nvox zeroed)
       const int* __restrict__ in_idx,   // [nvox*27]
       const int* __restrict__ mask,     // [nvox*27] (0/1)
       const int8_t* __restrict__ wperm, // [WPERM_B] permuted weights
       const int8_t* __restrict__ af,    // [nvox*64] affine A-rows
       const int* __restrict__ mul1,     // [64]   (layer 1)
       const int* __restrict__ slopep,   // scalar (layer 1)
       const int* __restrict__ x32,      // [nvox*64] residual (layer 2)
       int8_t* __restrict__ q1out,       // layer-1 output
       int* __restrict__ out,            // layer-2 output
       int nvox, int ntiles)
{
    __shared__ int8_t wlds[WPERM_B];        // 112 KB weights
    __shared__ int s_off[4][2][OFFN];       // per-wave offset double-buffer, 27 KB

    const int tid  = threadIdx.x;
    const int lane = tid & 63;
    const int wv   = tid >> 6;
    const int row  = lane & 31;     // A row / B,D col
    const int half = lane >> 5;     // k-subblock / D row offset

    // fill wlds (linear, coalesced), one-time barrier
#pragma unroll
    for (int i = 0; i < WPERM_B / 4096; ++i) {
        const int o = i * 4096 + tid * 16;
        *(v4i*)(wlds + o) = *(const v4i*)(wperm + o);
    }
    __syncthreads();

    const int gw = blockIdx.x * 4 + wv;     // global wave id 0..1023
    const int nw = gridDim.x * 4;           // 1024
    const int cnt = (ntiles - 1 - gw) / nw + 1;

    const int mul2a    = (LAYER == 1) ? (mul1[row] << 1) : 0;
    const int mul2b    = (LAYER == 1) ? (mul1[32 + row] << 1) : 0;
    const int slope128 = (LAYER == 1) ? ((*slopep) << 7) : 0;

    // prologue: off(t0) -> slot 0
    int t = gw;
    {
        const size_t base = (size_t)t * OFFN;
#pragma unroll
        for (int i2 = 0; i2 < 14; ++i2) {
            const int e = lane + 64 * i2;
            if (e < OFFN) {
                const int a = in_idx[base + e], m = mask[base + e];
                s_off[wv][0][e] = (m ? a : nvox) << 6;
            }
        }
    }

    for (int i = 0; i < cnt; ++i) {
        const int p = i & 1;
        const int nb = t * TV;

        // 1) gather A for tile t (s_off read: stride 27 dwords, 27 coprime 32 ->
        //    conflict-free; lane and lane+32 broadcast-share each entry)
        v4i a[KK][2], afr[2];
#pragma unroll
        for (int k = 0; k < KK; ++k) {
            const int off = s_off[wv][p][row * KK + k];
            a[k][0] = *(const v4i*)(fin + off + half * 16);
            a[k][1] = *(const v4i*)(fin + off + 32 + half * 16);
        }
        afr[0] = *(const v4i*)(af + (size_t)(nb + row) * CCH + half * 16);
        afr[1] = *(const v4i*)(af + (size_t)(nb + row) * CCH + 32 + half * 16);

        // 2) publish off(t+1) -> slot p^1 (per-wave private; in-wave lgkm order)
        {
            int tn = t + nw; if (tn >= ntiles) tn = ntiles - 1;
            const size_t bn = (size_t)tn * OFFN;
#pragma unroll
            for (int i2 = 0; i2 < 14; ++i2) {
                const int e = lane + 64 * i2;
                if (e < OFFN) {
                    const int qa = in_idx[bn + e], qm = mask[bn + e];
                    s_off[wv][p ^ 1][e] = (qm ? qa : nvox) << 6;
                }
            }
        }

        // 3) x32 prefetch (layer 2)
        v16i xr0, xr1;
        if (LAYER == 2) {
#pragma unroll
            for (int r = 0; r < 16; ++r) {
                const int vr = (r & 3) + 8 * (r >> 2) + 4 * half;
                xr0[r] = x32[(size_t)(nb + vr) * CCH + row];
                xr1[r] = x32[(size_t)(nb + vr) * CCH + 32 + row];
            }
        }

        // 4) 112 MFMAs: 28 slices x 2 cin-halves x 2 cout-halves
        v16i acc0 = {0,0,0,0,0,0,0,0,0,0,0,0,0,0,0,0};
        v16i acc1 = {0,0,0,0,0,0,0,0,0,0,0,0,0,0,0,0};
#pragma unroll
        for (int s = 0; s < NSL; ++s) {
#pragma unroll
            for (int h = 0; h < 2; ++h) {
                const v4i A = (s < KK) ? a[s][h] : afr[h];
                const int8_t* bp = wlds + (size_t)((s * 2 + h) * 2) * 1024 + lane * 16;
                acc0 = __builtin_amdgcn_mfma_i32_32x32x32_i8(A, *(const v4i*)bp, acc0, 0, 0, 0);
                acc1 = __builtin_amdgcn_mfma_i32_32x32x32_i8(A, *(const v4i*)(bp + 1024), acc1, 0, 0, 0);
            }
        }

        // 5) epilogue (affine already in acc): PReLU/requant or residual
#pragma unroll
        for (int r = 0; r < 16; ++r) {
            const int vr = (r & 3) + 8 * (r >> 2) + 4 * half;
            const size_t o = (size_t)(nb + vr) * CCH;
            if (LAYER == 1) {
                int v0 = acc0[r];
                int p0 = (v0 >= 0) ? v0 : __mulhi(v0, slope128);
                int q0v = __mulhi(p0, mul2a);
                q0v = q0v > 127 ? 127 : (q0v < -127 ? -127 : q0v);
                q1out[o + row] = (int8_t)q0v;
                int v1 = acc1[r];
                int p1 = (v1 >= 0) ? v1 : __mulhi(v1, slope128);
                int q1v = __mulhi(p1, mul2b);
                q1v = q1v > 127 ? 127 : (q1v < -127 ? -127 : q1v);
                q1out[o + 32 + row] = (int8_t)q1v;
            } else {
                out[o + row]      = acc0[r] + xr0[r];
                out[o + 32 + row] = acc1[r] + xr1[r];
            }
        }
        t += nw;
    }
}

extern "C" void kernel_launch(void* const* d_in, const int* in_sizes, int n_in,
                              void* d_out, int out_size, void* d_ws, size_t ws_size,
                              hipStream_t stream) {
    // ALL integer inputs arrive as int32 on device, regardless of reference dtype.
    const int* x32    = (const int*)d_in[0];
    const int* in_idx = (const int*)d_in[1];
    const int* mask   = (const int*)d_in[2];
    const int* w1_32  = (const int*)d_in[3];
    const int* b1     = (const int*)d_in[4];
    const int* comp1  = (const int*)d_in[5];
    const int* w2_32  = (const int*)d_in[6];
    const int* b2     = (const int*)d_in[7];
    const int* comp2  = (const int*)d_in[8];
    const int* mul0   = (const int*)d_in[9];
    const int* mul1   = (const int*)d_in[10];
    const int* slope  = (const int*)d_in[11];

    const int nvox = in_sizes[0] / CCH;                 // 100000 (%32==0)
    const size_t fbytes = (size_t)(nvox + 1) * CCH;     // +1 zero row
    const size_t falign = (fbytes + 255) & ~(size_t)255;
    const size_t walign = ((size_t)WPERM_B + 255) & ~(size_t)255;

    int8_t* q0;
    int8_t* q1;
    int8_t* w1p;
    int8_t* w2p;
    int8_t* af;
    if (ws_size >= 3 * falign + 2 * walign) {
        q0  = (int8_t*)d_ws;
        q1  = q0 + falign;
        w1p = q1 + falign;
        w2p = w1p + walign;
        af  = w2p + walign;
    } else {
        // stage q0 in d_out's bytes (dead after conv1; conv2 rewrites d_out fully)
        q0  = (int8_t*)d_out;
        q1  = (int8_t*)d_ws;
        w1p = q1 + falign;
        w2p = w1p + walign;
        af  = w2p + walign;
    }

    const int total4 = (nvox * CCH) / 4;                          // 1.6e6
    const int pb_w  = (2 * WPERM_B + 32 + 255) / 256;             // 897
    const int pb_af = (nvox + 255) / 256;                         // 391
    const int pb_rq = (total4 + 255) / 256;                       // 6250
    k_prep<<<pb_w + pb_af + pb_rq, 256, 0, stream>>>(
        x32, mul0, w1_32, w2_32, comp1, b1, comp2, b2, mask,
        w1p, w2p, (int*)q0, (int*)q1, af, pb_w, pb_af, nvox, total4);

    const int ntiles = nvox / TV;                       // 3125 (exact)
    const int cblocks = 256;                            // 1 block/CU, 4 waves each
    k_conv<1><<<cblocks, 256, 0, stream>>>(q0, in_idx, mask, w1p, af,
                                           mul1, slope, nullptr,
                                           q1, nullptr, nvox, ntiles);
    k_conv<2><<<cblocks, 256, 0, stream>>>(q1, in_idx, mask, w2p, af,
                                           nullptr, nullptr, x32,
                                           nullptr, (int*)d_out, nvox, ntiles);
}

// Round 12
// 197.150 us; speedup vs baseline: 1.1698x; 1.1698x over previous
//
#include <hip/hip_runtime.h>
#include <hip/hip_cooperative_groups.h>
#include <stdint.h>

namespace cg = cooperative_groups;

#define CCH 64
#define KK 27
#define WN (KK * CCH * CCH)        // 110592
#define WEXT (28 * CCH * CCH)      // 114688 per layer (27 conv slices + affine)

typedef int v4i __attribute__((ext_vector_type(4)));

struct ConvShared {
    int off[2][16][36];        // padded gather offsets: [slot][row][wv*8+j]
    v4i red[2][4][4][64];      // [parity][writer][group][lane]
};

// conv phase: k-split MFMA, 1 barrier/tile, software-pipelined reduction (r10).
// s_off packed: lane reads its 7 offsets via 2x ds_read_b128 (16B-aligned,
// row stride 144B -> 2-way bank alias = free).
template <int LAYER>
__device__ void conv_phase(
    ConvShared& sh,
    const int8_t* __restrict__ fin, const int* __restrict__ in_idx,
    const int* __restrict__ mask, const int8_t* __restrict__ wext,
    const int8_t* __restrict__ af, const int* __restrict__ mul1,
    const int* __restrict__ slopep, const int* __restrict__ x32,
    int8_t* __restrict__ q1out, int* __restrict__ out,
    int nvox, int ntiles)
{
    const int tid  = threadIdx.x;
    const int lane = tid & 63;
    const int wv   = tid >> 6;
    const int arow = lane & 15;
    const int srow = lane >> 4;
    const int col  = wv * 16 + arow;

    // publish-entry mapping (computed once): entry e -> (row, slice) -> slot
    const int e0 = tid;
    const int e1 = tid + 176;            // 176..431 (dup writes benign)
    const int r0 = e0 / 27, s0 = e0 - r0 * 27;
    const int r1 = e1 / 27, s1 = e1 - r1 * 27;
    const int slot0 = r0 * 36 + (s0 / 7) * 8 + (s0 % 7);
    const int slot1 = r1 * 36 + (s1 / 7) * 8 + (s1 % 7);
    int* const offl = &sh.off[0][0][0];
    const int OFFSTR = 16 * 36;          // dwords per parity slot

    v4i wreg[7][4];
#pragma unroll
    for (int j = 0; j < 7; ++j)
#pragma unroll
        for (int g = 0; g < 4; ++g)
            wreg[j][g] = *(const v4i*)(wext +
                ((size_t)((7 * wv + j) * CCH + g * 16 + arow)) * CCH + srow * 16);

    const int mul2     = (LAYER == 1) ? (mul1[col] << 1) : 0;
    const int slope128 = (LAYER == 1) ? ((*slopep) << 7) : 0;

    const int stride = gridDim.x;
    const int t0 = blockIdx.x;
    const int cnt = (ntiles - 1 - t0) / stride + 1;

    v4i aA[7], aB[7];
    v4i accP = {0, 0, 0, 0};

#define GATHER_A(AN, SN, NB)                                                   \
    {                                                                          \
        const v4i o0_ = *(const v4i*)&sh.off[SN][arow][wv * 8];                \
        const v4i o1_ = *(const v4i*)&sh.off[SN][arow][wv * 8 + 4];            \
        const int offs_[7] = {o0_[0], o0_[1], o0_[2], o0_[3],                  \
                              o1_[0], o1_[1], o1_[2]};                         \
        _Pragma("unroll")                                                      \
        for (int j = 0; j < 7; ++j) {                                          \
            if (wv == 3 && j == 6) {                                           \
                AN[6] = *(const v4i*)(af + (size_t)((NB) + arow) * CCH + srow * 16); \
            } else {                                                           \
                AN[j] = *(const v4i*)(fin + offs_[j] + srow * 16);             \
            }                                                                  \
        }                                                                      \
    }

#define EPILOGUE(TOT, NBP, X0, X1, X2, X3)                                     \
    if (LAYER == 1) {                                                          \
        int8_t* rp_ = q1out + (size_t)((NBP) + srow * 4) * CCH + col;          \
        _Pragma("unroll")                                                      \
        for (int r = 0; r < 4; ++r) {                                          \
            const int v_ = TOT[r];                                             \
            const int p_ = (v_ >= 0) ? v_ : __mulhi(v_, slope128);             \
            int q_ = __mulhi(p_, mul2);                                        \
            q_ = q_ > 127 ? 127 : (q_ < -127 ? -127 : q_);                     \
            rp_[r * CCH] = (int8_t)q_;                                         \
        }                                                                      \
    } else {                                                                   \
        int* rp_ = out + (size_t)((NBP) + srow * 4) * CCH + col;               \
        rp_[0 * CCH] = TOT[0] + X0;                                            \
        rp_[1 * CCH] = TOT[1] + X1;                                            \
        rp_[2 * CCH] = TOT[2] + X2;                                            \
        rp_[3 * CCH] = TOT[3] + X3;                                            \
    }

#define ITER(AC, AN, P, DO_EPI)                                                \
    do {                                                                       \
        int tp2_ = t + 2 * stride; if (tp2_ >= ntiles) tp2_ = ntiles - 1;      \
        const size_t b2_ = (size_t)tp2_ * (16 * KK);                           \
        const int qa0_ = in_idx[b2_ + e0], qm0_ = mask[b2_ + e0];              \
        const int qa1_ = in_idx[b2_ + e1], qm1_ = mask[b2_ + e1];              \
        const int nbp_ = (t - stride) * 16;                                    \
        int xr0_ = 0, xr1_ = 0, xr2_ = 0, xr3_ = 0;                            \
        if (DO_EPI && LAYER == 2) {                                            \
            const int* xp_ = x32 + (size_t)(nbp_ + srow * 4) * CCH + col;      \
            xr0_ = xp_[0 * CCH]; xr1_ = xp_[1 * CCH];                          \
            xr2_ = xp_[2 * CCH]; xr3_ = xp_[3 * CCH];                          \
        }                                                                      \
        GATHER_A(AN, (P) ^ 1, (t + stride < ntiles ? (t + stride) * 16 : (ntiles - 1) * 16)) \
        __builtin_amdgcn_sched_barrier(0);                                     \
        v4i acc0 = {0,0,0,0}, acc1 = {0,0,0,0}, acc2 = {0,0,0,0}, acc3 = {0,0,0,0}; \
        __builtin_amdgcn_s_setprio(1);                                         \
        _Pragma("unroll")                                                      \
        for (int j = 0; j < 7; ++j) {                                          \
            acc0 = __builtin_amdgcn_mfma_i32_16x16x64_i8(AC[j], wreg[j][0], acc0, 0, 0, 0); \
            acc1 = __builtin_amdgcn_mfma_i32_16x16x64_i8(AC[j], wreg[j][1], acc1, 0, 0, 0); \
            acc2 = __builtin_amdgcn_mfma_i32_16x16x64_i8(AC[j], wreg[j][2], acc2, 0, 0, 0); \
            acc3 = __builtin_amdgcn_mfma_i32_16x16x64_i8(AC[j], wreg[j][3], acc3, 0, 0, 0); \
        }                                                                      \
        __builtin_amdgcn_s_setprio(0);                                         \
        if (wv != 0) sh.red[P][wv][0][lane] = acc0;                            \
        if (wv != 1) sh.red[P][wv][1][lane] = acc1;                            \
        if (wv != 2) sh.red[P][wv][2][lane] = acc2;                            \
        if (wv != 3) sh.red[P][wv][3][lane] = acc3;                            \
        if (DO_EPI) {                                                          \
            v4i tot = accP;                                                    \
            _Pragma("unroll")                                                  \
            for (int w = 0; w < 4; ++w) {                                      \
                if (w != wv) {                                                 \
                    const v4i r_ = sh.red[(P) ^ 1][w][wv][lane];               \
                    tot[0] += r_[0]; tot[1] += r_[1];                          \
                    tot[2] += r_[2]; tot[3] += r_[3];                          \
                }                                                              \
            }                                                                  \
            EPILOGUE(tot, nbp_, xr0_, xr1_, xr2_, xr3_)                        \
        }                                                                      \
        offl[(P) * OFFSTR + slot0] = (qm0_ ? qa0_ : nvox) << 6;                \
        offl[(P) * OFFSTR + slot1] = (qm1_ ? qa1_ : nvox) << 6;                \
        accP = (wv == 0) ? acc0 : (wv == 1) ? acc1 : (wv == 2) ? acc2 : acc3;  \
        asm volatile("s_waitcnt lgkmcnt(0)" ::: "memory");                     \
        __builtin_amdgcn_s_barrier();                                          \
    } while (0)

    // ---- prologue: off[t0]->slot0, off[t1]->slot1, gather A(t0)->aA ----
    int pa0, pa1, pm0, pm1;
    {
        const size_t base = (size_t)t0 * (16 * KK);
        const int a0 = in_idx[base + e0], m0 = mask[base + e0];
        const int a1 = in_idx[base + e1], m1 = mask[base + e1];
        offl[0 * OFFSTR + slot0] = (m0 ? a0 : nvox) << 6;
        offl[0 * OFFSTR + slot1] = (m1 ? a1 : nvox) << 6;
    }
    {
        int t1c = t0 + stride; if (t1c >= ntiles) t1c = ntiles - 1;
        const size_t base = (size_t)t1c * (16 * KK);
        pa0 = in_idx[base + e0]; pm0 = mask[base + e0];
        pa1 = in_idx[base + e1]; pm1 = mask[base + e1];
    }
    __syncthreads();
    GATHER_A(aA, 0, t0 * 16)
    offl[1 * OFFSTR + slot0] = (pm0 ? pa0 : nvox) << 6;
    offl[1 * OFFSTR + slot1] = (pm1 ? pa1 : nvox) << 6;
    asm volatile("s_waitcnt lgkmcnt(0)" ::: "memory");
    __builtin_amdgcn_s_barrier();

    // ---- main loop ----
    int t = t0;
    ITER(aA, aB, 0, 0);
    t += stride;
    int i = 1;
    while (i < cnt) {
        ITER(aB, aA, 1, 1);
        ++i; t += stride; if (i >= cnt) break;
        ITER(aA, aB, 0, 1);
        ++i; t += stride;
    }

    // ---- drain: epilogue for the last tile ----
    {
        const int pl = (cnt - 1) & 1;
        const int nbl = (t0 + (cnt - 1) * stride) * 16;
        int x0 = 0, x1 = 0, x2 = 0, x3 = 0;
        if (LAYER == 2) {
            const int* xp_ = x32 + (size_t)(nbl + srow * 4) * CCH + col;
            x0 = xp_[0 * CCH]; x1 = xp_[1 * CCH];
            x2 = xp_[2 * CCH]; x3 = xp_[3 * CCH];
        }
        v4i tot = accP;
#pragma unroll
        for (int w = 0; w < 4; ++w) {
            if (w != wv) {
                const v4i r_ = sh.red[pl][w][wv][lane];
                tot[0] += r_[0]; tot[1] += r_[1];
                tot[2] += r_[2]; tot[3] += r_[3];
            }
        }
        EPILOGUE(tot, nbl, x0, x1, x2, x3)
    }
#undef ITER
#undef EPILOGUE
#undef GATHER_A
}

// Fused cooperative kernel: prep -> sync -> conv1 -> sync -> conv2.
__global__ void __launch_bounds__(256, 2) k_fused(
    const int* x32, const int* in_idx, const int* mask,
    const int* w1_32, const int* b1, const int* comp1,
    const int* w2_32, const int* b2, const int* comp2,
    const int* mul0p, const int* mul1, const int* slopep,
    int8_t* q0, int8_t* q1, int8_t* w1e, int8_t* w2e, int8_t* af,
    int* outp, int nvox, int ntiles, int total4)
{
    __shared__ ConvShared sh;
    const int gsz = gridDim.x * 256;
    const int g   = blockIdx.x * 256 + threadIdx.x;

    // ---- phase 0: prep (grid-stride; all independent) ----
    // (exact requant: (x*mul)>>31 == mulhi(x, mul<<1))
    for (int u = g; u < 2 * WEXT; u += gsz) {
        const int which = u >= WEXT;
        const int v_ = which ? u - WEXT : u;
        int val;
        if (v_ < WN) {
            val = (which ? w2_32 : w1_32)[v_];
        } else {
            const int u2 = v_ - WN;
            const int colx = u2 >> 6, j = u2 & 63;
            const int* comp = which ? comp2 : comp1;
            const int* bias = which ? b2 : b1;
            if (j < 27)       val = comp[j * CCH + colx] >> 2;        // A=4*mask
            else if (j < 54)  val = comp[(j - 27) * CCH + colx] & 3;  // A=1*mask
            else if (j == 54) val = bias[colx] >> 6;                  // A=64
            else if (j == 55) val = bias[colx] & 63;                  // A=1
            else              val = 0;
        }
        (which ? w2e : w1e)[v_] = (int8_t)val;
    }
    for (int vox = g; vox < nvox; vox += gsz) {
        int m[27];
#pragma unroll
        for (int k = 0; k < 27; ++k)
            m[k] = mask[(size_t)vox * 27 + k] ? 1 : 0;
        v4i d[4];
#pragma unroll
        for (int di = 0; di < 16; ++di) {
            int pk = 0;
#pragma unroll
            for (int b = 0; b < 4; ++b) {
                const int ch = di * 4 + b;
                int bv = 0;
                if (ch < 27)       bv = m[ch] << 2;
                else if (ch < 54)  bv = m[ch - 27];
                else if (ch == 54) bv = 64;
                else if (ch == 55) bv = 1;
                pk |= bv << (8 * b);
            }
            d[di >> 2][di & 3] = pk;
        }
        v4i* dst = (v4i*)(af + (size_t)vox * 64);
        dst[0] = d[0]; dst[1] = d[1]; dst[2] = d[2]; dst[3] = d[3];
    }
    {
        const int mul2 = (*mul0p) << 1;
        for (int i = g; i < total4; i += gsz) {
            const int4 v = ((const int4*)x32)[i];
            int r = 0, q;
            q = __mulhi(v.x, mul2); q = q > 127 ? 127 : (q < -127 ? -127 : q); r |= (q & 0xff);
            q = __mulhi(v.y, mul2); q = q > 127 ? 127 : (q < -127 ? -127 : q); r |= (q & 0xff) << 8;
            q = __mulhi(v.z, mul2); q = q > 127 ? 127 : (q < -127 ? -127 : q); r |= (q & 0xff) << 16;
            q = __mulhi(v.w, mul2); q = q > 127 ? 127 : (q < -127 ? -127 : q); r |= (q & 0xff) << 24;
            ((int*)q0)[i] = r;
        }
    }
    if (g < 16)      ((int*)q0)[(size_t)nvox * 16 + g] = 0;       // zero row q0
    else if (g < 32) ((int*)q1)[(size_t)nvox * 16 + (g - 16)] = 0; // zero row q1

    __threadfence();
    cg::this_grid().sync();

    // ---- phase 1: conv layer 1 (q0 -> q1) ----
    conv_phase<1>(sh, q0, in_idx, mask, w1e, af, mul1, slopep,
                  nullptr, q1, nullptr, nvox, ntiles);

    __threadfence();
    cg::this_grid().sync();

    // ---- phase 2: conv layer 2 (q1 -> out, + residual) ----
    conv_phase<2>(sh, q1, in_idx, mask, w2e, af, nullptr, nullptr,
                  x32, nullptr, outp, nvox, ntiles);
}

extern "C" void kernel_launch(void* const* d_in, const int* in_sizes, int n_in,
                              void* d_out, int out_size, void* d_ws, size_t ws_size,
                              hipStream_t stream) {
    // ALL integer inputs arrive as int32 on device, regardless of reference dtype.
    const int* x32    = (const int*)d_in[0];
    const int* in_idx = (const int*)d_in[1];
    const int* mask   = (const int*)d_in[2];
    const int* w1_32  = (const int*)d_in[3];
    const int* b1     = (const int*)d_in[4];
    const int* comp1  = (const int*)d_in[5];
    const int* w2_32  = (const int*)d_in[6];
    const int* b2     = (const int*)d_in[7];
    const int* comp2  = (const int*)d_in[8];
    const int* mul0   = (const int*)d_in[9];
    const int* mul1   = (const int*)d_in[10];
    const int* slope  = (const int*)d_in[11];

    const int nvox = in_sizes[0] / CCH;                 // 100000 (%16==0)
    const size_t fbytes = (size_t)(nvox + 1) * CCH;     // +1 zero row
    const size_t falign = (fbytes + 255) & ~(size_t)255;
    const size_t walign = ((size_t)WEXT + 255) & ~(size_t)255;

    int8_t* q0;
    int8_t* q1;
    int8_t* w1e;
    int8_t* w2e;
    int8_t* af;
    if (ws_size >= 3 * falign + 2 * walign) {
        q0  = (int8_t*)d_ws;
        q1  = q0 + falign;
        w1e = q1 + falign;
        w2e = w1e + walign;
        af  = w2e + walign;
    } else {
        q0  = (int8_t*)d_out;   // dead after conv1; conv2 rewrites d_out fully
        q1  = (int8_t*)d_ws;
        w1e = q1 + falign;
        w2e = w1e + walign;
        af  = w2e + walign;
    }

    int ntiles = nvox / 16;                             // 6250 (exact)
    int total4 = nvox * 16;
    int* outp  = (int*)d_out;

    int maxb = 0;
    (void)hipOccupancyMaxActiveBlocksPerMultiprocessor(
        &maxb, reinterpret_cast<const void*>(k_fused), 256, 0);
    if (maxb < 1) maxb = 1;
    int grid = maxb * 256;
    if (grid > 512) grid = 512;
    if (grid > ntiles) grid = ntiles;

    void* args[] = {
        (void*)&x32, (void*)&in_idx, (void*)&mask,
        (void*)&w1_32, (void*)&b1, (void*)&comp1,
        (void*)&w2_32, (void*)&b2, (void*)&comp2,
        (void*)&mul0, (void*)&mul1, (void*)&slope,
        (void*)&q0, (void*)&q1, (void*)&w1e, (void*)&w2e, (void*)&af,
        (void*)&outp, (void*)&nvox, (void*)&ntiles, (void*)&total4
    };
    hipLaunchCooperativeKernel(reinterpret_cast<void*>(k_fused),
                               dim3(grid), dim3(256), args, 0, stream);
}

// Round 13
// 56.712 us; speedup vs baseline: 4.0667x; 3.4764x over previous
//
#include <hip/hip_runtime.h>
#include <stdint.h>

#define CCH 64
#define KK 27
#define WN (KK * CCH * CCH)   // 110592

typedef int v4i __attribute__((ext_vector_type(4)));

// ---------------- prep: weights + affine slice + af rows + requant + zero rows ----
// exact: (x*mul)>>31 == mulhi(x, mul<<1); (x*slope)>>25 == mulhi(x, slope<<7)
__global__ void __launch_bounds__(256) k_prep(
    const int* __restrict__ x32, const int* __restrict__ mul0p,
    const int* __restrict__ w1_32, const int* __restrict__ w2_32,
    const int* __restrict__ comp1, const int* __restrict__ b1,
    const int* __restrict__ comp2, const int* __restrict__ b2,
    const int* __restrict__ mask,
    int8_t* __restrict__ w1e, int8_t* __restrict__ w2e,
    int* __restrict__ q0, int* __restrict__ q1, int8_t* __restrict__ af,
    int pb1, int af_blocks, int nvox, int total4)
{
    const int bid = blockIdx.x;
    if (bid < pb1) {
        const int gtid = bid * 256 + threadIdx.x;
        if (gtid < WN) {
            w1e[gtid] = (int8_t)w1_32[gtid];
        } else if (gtid < 2 * WN) {
            w2e[gtid - WN] = (int8_t)w2_32[gtid - WN];
        } else if (gtid < 2 * WN + 8192) {
            int u = gtid - 2 * WN;
            const int which = u >> 12;
            u &= 4095;
            const int col = u >> 6, j = u & 63;
            const int* comp = which ? comp2 : comp1;
            const int* bias = which ? b2 : b1;
            int v;
            if (j < 27)       v = comp[j * CCH + col] >> 2;       // pairs A=4*mask
            else if (j < 54)  v = comp[(j - 27) * CCH + col] & 3; // pairs A=1*mask
            else if (j == 54) v = bias[col] >> 6;                 // pairs A=64
            else if (j == 55) v = bias[col] & 63;                 // pairs A=1
            else              v = 0;
            (which ? w2e : w1e)[27 * 4096 + col * 64 + j] = (int8_t)v;
        } else {
            const int u = gtid - 2 * WN - 8192;   // zero rows (row nvox of q0,q1)
            if (u < 16)       q0[(size_t)nvox * 16 + u] = 0;
            else if (u < 32)  q1[(size_t)nvox * 16 + (u - 16)] = 0;
        }
    } else if (bid < pb1 + af_blocks) {
        // affine A-rows: af[vox][j] = j<27?4m : j<54?m : j==54?64 : j==55?1 : 0
        const int vox = (bid - pb1) * 256 + threadIdx.x;
        if (vox < nvox) {
            int m[27];
#pragma unroll
            for (int k = 0; k < 27; ++k)
                m[k] = mask[(size_t)vox * 27 + k] ? 1 : 0;
            v4i d0, d1, d2, d3;
#pragma unroll
            for (int di = 0; di < 16; ++di) {
                int pk = 0;
#pragma unroll
                for (int b = 0; b < 4; ++b) {
                    const int ch = di * 4 + b;
                    int bv = 0;
                    if (ch < 27)       bv = m[ch] << 2;
                    else if (ch < 54)  bv = m[ch - 27];
                    else if (ch == 54) bv = 64;
                    else if (ch == 55) bv = 1;
                    pk |= bv << (8 * b);
                }
                if (di < 4)       d0[di] = pk;
                else if (di < 8)  d1[di - 4] = pk;
                else if (di < 12) d2[di - 8] = pk;
                else              d3[di - 12] = pk;
            }
            v4i* dst = (v4i*)(af + (size_t)vox * 64);
            dst[0] = d0; dst[1] = d1; dst[2] = d2; dst[3] = d3;
        }
    } else {
        const int i = (bid - pb1 - af_blocks) * 256 + threadIdx.x;
        if (i < total4) {
            const int mul2 = (*mul0p) << 1;
            const int4 v = ((const int4*)x32)[i];
            int r = 0, q;
            q = __mulhi(v.x, mul2); q = q > 127 ? 127 : (q < -127 ? -127 : q); r |= (q & 0xff);
            q = __mulhi(v.y, mul2); q = q > 127 ? 127 : (q < -127 ? -127 : q); r |= (q & 0xff) << 8;
            q = __mulhi(v.z, mul2); q = q > 127 ? 127 : (q < -127 ? -127 : q); r |= (q & 0xff) << 16;
            q = __mulhi(v.w, mul2); q = q > 127 ? 127 : (q < -127 ? -127 : q); r |= (q & 0xff) << 24;
            q0[i] = r;
        }
    }
}

// k-split MFMA conv, 1 barrier/tile, software-pipelined cross-wave reduction.
//  - wave wv owns k-slices [7wv,7wv+7) for all 64 out channels; wv3's 7th slice
//    is the affine slice whose A-rows are the precomputed af[] table
//  - s_off [2][16][36]: packed per-(row,wave) groups of 8 offsets; a lane reads
//    its 7 gather offsets with 2x ds_read_b128 (row stride 144B -> 2-way, free)
//  - A-fragments register-double-buffered one tile ahead; tile t's foreign
//    partials written to s_red[t&1], reduced + stored in the NEXT iteration
//  - one lgkmcnt(0)+s_barrier per tile; vmem loads stay in flight across it
// REQUIRES nvox % 16 == 0 (100000 = 6250*16).
template <int LAYER>
__global__ void __launch_bounds__(256, 2)
k_conv(const int8_t* __restrict__ fin,   // [(nvox+1)*64] int8 (row nvox = zeros)
       const int* __restrict__ in_idx,   // [nvox*27]
       const int* __restrict__ mask,     // [nvox*27] (0/1)
       const int8_t* __restrict__ wext,  // [28*64*64] packed int8
       const int8_t* __restrict__ af,    // [nvox*64] affine A-rows
       const int* __restrict__ mul1,     // [64]   (layer 1)
       const int* __restrict__ slopep,   // scalar (layer 1)
       const int* __restrict__ x32,      // [nvox*64] residual (layer 2)
       int8_t* __restrict__ q1out,       // layer-1 output
       int* __restrict__ out,            // layer-2 output
       int nvox, int ntiles)
{
    __shared__ int s_off[2][16][36];          // [slot][row][wv*8+j] byte offsets
    __shared__ v4i s_red[2][4][4][64];        // [parity][writer][group][lane]

    const int tid  = threadIdx.x;
    const int lane = tid & 63;
    const int wv   = tid >> 6;
    const int arow = lane & 15;
    const int srow = lane >> 4;
    const int col  = wv * 16 + arow;

    // publish-entry mapping: entry e (row*27+slice) -> packed slot row*36+(s/7)*8+(s%7)
    const int e0 = tid;            // 0..255
    const int e1 = tid + 176;      // 176..431 (dup writes benign: same values)
    const int r0 = e0 / 27, s0 = e0 - r0 * 27;
    const int r1 = e1 / 27, s1 = e1 - r1 * 27;
    const int slot0 = r0 * 36 + (s0 / 7) * 8 + (s0 % 7);
    const int slot1 = r1 * 36 + (s1 / 7) * 8 + (s1 % 7);
    int* const offl = &s_off[0][0][0];
    const int OFFSTR = 16 * 36;

    v4i wreg[7][4];
#pragma unroll
    for (int j = 0; j < 7; ++j)
#pragma unroll
        for (int g = 0; g < 4; ++g)
            wreg[j][g] = *(const v4i*)(wext +
                ((size_t)((7 * wv + j) * CCH + g * 16 + arow)) * CCH + srow * 16);

    const int mul2     = (LAYER == 1) ? (mul1[col] << 1) : 0;
    const int slope128 = (LAYER == 1) ? ((*slopep) << 7) : 0;

    const int stride = gridDim.x;
    const int t0 = blockIdx.x;
    if (t0 >= ntiles) return;
    const int cnt = (ntiles - 1 - t0) / stride + 1;

    v4i aA[7], aB[7];
    v4i accP = {0, 0, 0, 0};

#define GATHER_A(AN, SN, NB)                                                   \
    {                                                                          \
        const v4i o0_ = *(const v4i*)&s_off[SN][arow][wv * 8];                 \
        const v4i o1_ = *(const v4i*)&s_off[SN][arow][wv * 8 + 4];             \
        const int offs_[7] = {o0_[0], o0_[1], o0_[2], o0_[3],                  \
                              o1_[0], o1_[1], o1_[2]};                         \
        _Pragma("unroll")                                                      \
        for (int j = 0; j < 7; ++j) {                                          \
            if (wv == 3 && j == 6) {                                           \
                AN[6] = *(const v4i*)(af + (size_t)((NB) + arow) * CCH + srow * 16); \
            } else {                                                           \
                AN[j] = *(const v4i*)(fin + offs_[j] + srow * 16);             \
            }                                                                  \
        }                                                                      \
    }

#define EPILOGUE(TOT, NBP, X0, X1, X2, X3)                                     \
    if (LAYER == 1) {                                                          \
        int8_t* rp_ = q1out + (size_t)((NBP) + srow * 4) * CCH + col;          \
        _Pragma("unroll")                                                      \
        for (int r = 0; r < 4; ++r) {                                          \
            const int v_ = TOT[r];                                             \
            const int p_ = (v_ >= 0) ? v_ : __mulhi(v_, slope128);             \
            int q_ = __mulhi(p_, mul2);                                        \
            q_ = q_ > 127 ? 127 : (q_ < -127 ? -127 : q_);                     \
            rp_[r * CCH] = (int8_t)q_;                                         \
        }                                                                      \
    } else {                                                                   \
        int* rp_ = out + (size_t)((NBP) + srow * 4) * CCH + col;               \
        rp_[0 * CCH] = TOT[0] + X0;                                            \
        rp_[1 * CCH] = TOT[1] + X1;                                            \
        rp_[2 * CCH] = TOT[2] + X2;                                            \
        rp_[3 * CCH] = TOT[3] + X3;                                            \
    }

#define ITER(AC, AN, P, DO_EPI)                                                \
    do {                                                                       \
        /* (a) prefetch off[t+2] -> regs; x32 rows of tile t-1 */              \
        int tp2_ = t + 2 * stride; if (tp2_ >= ntiles) tp2_ = ntiles - 1;      \
        const size_t b2_ = (size_t)tp2_ * (16 * KK);                           \
        const int qa0_ = in_idx[b2_ + e0], qm0_ = mask[b2_ + e0];              \
        const int qa1_ = in_idx[b2_ + e1], qm1_ = mask[b2_ + e1];              \
        const int nbp_ = (t - stride) * 16;                                    \
        int xr0_ = 0, xr1_ = 0, xr2_ = 0, xr3_ = 0;                            \
        if (DO_EPI && LAYER == 2) {                                            \
            const int* xp_ = x32 + (size_t)(nbp_ + srow * 4) * CCH + col;      \
            xr0_ = xp_[0 * CCH]; xr1_ = xp_[1 * CCH];                          \
            xr2_ = xp_[2 * CCH]; xr3_ = xp_[3 * CCH];                          \
        }                                                                      \
        /* (b) issue next tile's A gathers */                                  \
        GATHER_A(AN, (P) ^ 1, (t + stride < ntiles ? (t + stride) * 16 : (ntiles - 1) * 16)) \
        __builtin_amdgcn_sched_barrier(0);                                     \
        /* (c) 28 MFMAs on AC */                                               \
        v4i acc0 = {0,0,0,0}, acc1 = {0,0,0,0}, acc2 = {0,0,0,0}, acc3 = {0,0,0,0}; \
        __builtin_amdgcn_s_setprio(1);                                         \
        _Pragma("unroll")                                                      \
        for (int j = 0; j < 7; ++j) {                                          \
            acc0 = __builtin_amdgcn_mfma_i32_16x16x64_i8(AC[j], wreg[j][0], acc0, 0, 0, 0); \
            acc1 = __builtin_amdgcn_mfma_i32_16x16x64_i8(AC[j], wreg[j][1], acc1, 0, 0, 0); \
            acc2 = __builtin_amdgcn_mfma_i32_16x16x64_i8(AC[j], wreg[j][2], acc2, 0, 0, 0); \
            acc3 = __builtin_amdgcn_mfma_i32_16x16x64_i8(AC[j], wreg[j][3], acc3, 0, 0, 0); \
        }                                                                      \
        __builtin_amdgcn_s_setprio(0);                                         \
        /* (d) write foreign partials for tile t into s_red[P] */              \
        if (wv != 0) s_red[P][wv][0][lane] = acc0;                             \
        if (wv != 1) s_red[P][wv][1][lane] = acc1;                             \
        if (wv != 2) s_red[P][wv][2][lane] = acc2;                             \
        if (wv != 3) s_red[P][wv][3][lane] = acc3;                             \
        /* (e) reduce + store tile t-1 from s_red[P^1] + accP */               \
        if (DO_EPI) {                                                          \
            v4i tot = accP;                                                    \
            _Pragma("unroll")                                                  \
            for (int w = 0; w < 4; ++w) {                                      \
                if (w != wv) {                                                 \
                    const v4i r_ = s_red[(P) ^ 1][w][wv][lane];                \
                    tot[0] += r_[0]; tot[1] += r_[1];                          \
                    tot[2] += r_[2]; tot[3] += r_[3];                          \
                }                                                              \
            }                                                                  \
            EPILOGUE(tot, nbp_, xr0_, xr1_, xr2_, xr3_)                        \
        }                                                                      \
        /* (f) publish off[t+2] -> slot P; keep own partial */                 \
        offl[(P) * OFFSTR + slot0] = (qm0_ ? qa0_ : nvox) << 6;                \
        offl[(P) * OFFSTR + slot1] = (qm1_ ? qa1_ : nvox) << 6;                \
        accP = (wv == 0) ? acc0 : (wv == 1) ? acc1 : (wv == 2) ? acc2 : acc3;  \
        asm volatile("s_waitcnt lgkmcnt(0)" ::: "memory");                     \
        __builtin_amdgcn_s_barrier();                                          \
    } while (0)

    // ---- prologue: off[t0]->slot0, off[t1]->slot1, gather A(t0)->aA ----
    int pa0, pa1, pm0, pm1;
    {
        const size_t base = (size_t)t0 * (16 * KK);
        const int a0 = in_idx[base + e0], m0 = mask[base + e0];
        const int a1 = in_idx[base + e1], m1 = mask[base + e1];
        offl[0 * OFFSTR + slot0] = (m0 ? a0 : nvox) << 6;
        offl[0 * OFFSTR + slot1] = (m1 ? a1 : nvox) << 6;
    }
    {
        int t1c = t0 + stride; if (t1c >= ntiles) t1c = ntiles - 1;
        const size_t base = (size_t)t1c * (16 * KK);
        pa0 = in_idx[base + e0]; pm0 = mask[base + e0];
        pa1 = in_idx[base + e1]; pm1 = mask[base + e1];
    }
    __syncthreads();
    GATHER_A(aA, 0, t0 * 16)
    offl[1 * OFFSTR + slot0] = (pm0 ? pa0 : nvox) << 6;
    offl[1 * OFFSTR + slot1] = (pm1 ? pa1 : nvox) << 6;
    asm volatile("s_waitcnt lgkmcnt(0)" ::: "memory");
    __builtin_amdgcn_s_barrier();

    // ---- main loop ----
    int t = t0;
    ITER(aA, aB, 0, 0);
    t += stride;
    int i = 1;
    while (i < cnt) {
        ITER(aB, aA, 1, 1);
        ++i; t += stride; if (i >= cnt) break;
        ITER(aA, aB, 0, 1);
        ++i; t += stride;
    }

    // ---- drain: epilogue for the last tile ----
    {
        const int pl = (cnt - 1) & 1;
        const int nbl = (t0 + (cnt - 1) * stride) * 16;
        int x0 = 0, x1 = 0, x2 = 0, x3 = 0;
        if (LAYER == 2) {
            const int* xp_ = x32 + (size_t)(nbl + srow * 4) * CCH + col;
            x0 = xp_[0 * CCH]; x1 = xp_[1 * CCH];
            x2 = xp_[2 * CCH]; x3 = xp_[3 * CCH];
        }
        v4i tot = accP;
#pragma unroll
        for (int w = 0; w < 4; ++w) {
            if (w != wv) {
                const v4i r_ = s_red[pl][w][wv][lane];
                tot[0] += r_[0]; tot[1] += r_[1];
                tot[2] += r_[2]; tot[3] += r_[3];
            }
        }
        EPILOGUE(tot, nbl, x0, x1, x2, x3)
    }
#undef ITER
#undef EPILOGUE
#undef GATHER_A
}

extern "C" void kernel_launch(void* const* d_in, const int* in_sizes, int n_in,
                              void* d_out, int out_size, void* d_ws, size_t ws_size,
                              hipStream_t stream) {
    // ALL integer inputs arrive as int32 on device, regardless of reference dtype.
    const int* x32    = (const int*)d_in[0];
    const int* in_idx = (const int*)d_in[1];
    const int* mask   = (const int*)d_in[2];
    const int* w1_32  = (const int*)d_in[3];
    const int* b1     = (const int*)d_in[4];
    const int* comp1  = (const int*)d_in[5];
    const int* w2_32  = (const int*)d_in[6];
    const int* b2     = (const int*)d_in[7];
    const int* comp2  = (const int*)d_in[8];
    const int* mul0   = (const int*)d_in[9];
    const int* mul1   = (const int*)d_in[10];
    const int* slope  = (const int*)d_in[11];

    const int nvox = in_sizes[0] / CCH;                 // 100000 (%16==0)
    const size_t wext_b = (size_t)28 * CCH * CCH;       // 114688 per layer
    const size_t fbytes = (size_t)(nvox + 1) * CCH;     // +1 zero row
    const size_t falign = (fbytes + 255) & ~(size_t)255;
    const size_t walign = (wext_b + 255) & ~(size_t)255;

    int8_t* q0;
    int8_t* q1;
    int8_t* w1e;
    int8_t* w2e;
    int8_t* af;
    if (ws_size >= 3 * falign + 2 * walign) {
        q0  = (int8_t*)d_ws;
        q1  = q0 + falign;
        w1e = q1 + falign;
        w2e = w1e + walign;
        af  = w2e + walign;
    } else {
        // stage q0 in d_out's bytes (dead after conv1; conv2 rewrites d_out fully)
        q0  = (int8_t*)d_out;
        q1  = (int8_t*)d_ws;
        w1e = q1 + falign;
        w2e = w1e + walign;
        af  = w2e + walign;
    }

    const int total4 = (nvox * CCH) / 4;                          // 1.6e6
    const int pb1 = (2 * WN + 8192 + 32 + 255) / 256;             // 897
    const int af_blocks  = (nvox + 255) / 256;                    // 391
    const int req_blocks = (total4 + 255) / 256;                  // 6250
    k_prep<<<pb1 + af_blocks + req_blocks, 256, 0, stream>>>(
        x32, mul0, w1_32, w2_32, comp1, b1, comp2, b2, mask,
        w1e, w2e, (int*)q0, (int*)q1, af, pb1, af_blocks, nvox, total4);

    const int ntiles = nvox / 16;                       // 6250 (exact)
    int cblocks = 512;                                  // 2 resident blocks/CU
    if (cblocks > ntiles) cblocks = ntiles;
    k_conv<1><<<cblocks, 256, 0, stream>>>(q0, in_idx, mask, w1e, af,
                                           mul1, slope, nullptr,
                                           q1, nullptr, nvox, ntiles);
    k_conv<2><<<cblocks, 256, 0, stream>>>(q1, in_idx, mask, w2e, af,
                                           nullptr, nullptr, x32,
                                           nullptr, (int*)d_out, nvox, ntiles);
}

// Round 14
// 56.627 us; speedup vs baseline: 4.0728x; 1.0015x over previous
//
#include <hip/hip_runtime.h>
#include <stdint.h>

#define CCH 64
#define KK 27
#define WN (KK * CCH * CCH)   // 110592

typedef int v4i __attribute__((ext_vector_type(4)));

// ---------------- prep: weights + affine slice + af rows + requant + zero rows ----
// exact: (x*mul)>>31 == mulhi(x, mul<<1); (x*slope)>>25 == mulhi(x, slope<<7)
__global__ void __launch_bounds__(256) k_prep(
    const int* __restrict__ x32, const int* __restrict__ mul0p,
    const int* __restrict__ w1_32, const int* __restrict__ w2_32,
    const int* __restrict__ comp1, const int* __restrict__ b1,
    const int* __restrict__ comp2, const int* __restrict__ b2,
    const int* __restrict__ mask,
    int8_t* __restrict__ w1e, int8_t* __restrict__ w2e,
    int* __restrict__ q0, int* __restrict__ q1, int8_t* __restrict__ af,
    int pb1, int af_blocks, int nvox, int total4)
{
    const int bid = blockIdx.x;
    if (bid < pb1) {
        const int gtid = bid * 256 + threadIdx.x;
        if (gtid < WN) {
            w1e[gtid] = (int8_t)w1_32[gtid];
        } else if (gtid < 2 * WN) {
            w2e[gtid - WN] = (int8_t)w2_32[gtid - WN];
        } else if (gtid < 2 * WN + 8192) {
            int u = gtid - 2 * WN;
            const int which = u >> 12;
            u &= 4095;
            const int col = u >> 6, j = u & 63;
            const int* comp = which ? comp2 : comp1;
            const int* bias = which ? b2 : b1;
            int v;
            if (j < 27)       v = comp[j * CCH + col] >> 2;       // pairs A=4*mask
            else if (j < 54)  v = comp[(j - 27) * CCH + col] & 3; // pairs A=1*mask
            else if (j == 54) v = bias[col] >> 6;                 // pairs A=64
            else if (j == 55) v = bias[col] & 63;                 // pairs A=1
            else              v = 0;
            (which ? w2e : w1e)[27 * 4096 + col * 64 + j] = (int8_t)v;
        } else {
            const int u = gtid - 2 * WN - 8192;   // zero rows (row nvox of q0,q1)
            if (u < 16)       q0[(size_t)nvox * 16 + u] = 0;
            else if (u < 32)  q1[(size_t)nvox * 16 + (u - 16)] = 0;
        }
    } else if (bid < pb1 + af_blocks) {
        // affine A-rows: af[vox][j] = j<27?4m : j<54?m : j==54?64 : j==55?1 : 0
        const int vox = (bid - pb1) * 256 + threadIdx.x;
        if (vox < nvox) {
            int m[27];
#pragma unroll
            for (int k = 0; k < 27; ++k)
                m[k] = mask[(size_t)vox * 27 + k] ? 1 : 0;
            v4i d0, d1, d2, d3;
#pragma unroll
            for (int di = 0; di < 16; ++di) {
                int pk = 0;
#pragma unroll
                for (int b = 0; b < 4; ++b) {
                    const int ch = di * 4 + b;
                    int bv = 0;
                    if (ch < 27)       bv = m[ch] << 2;
                    else if (ch < 54)  bv = m[ch - 27];
                    else if (ch == 54) bv = 64;
                    else if (ch == 55) bv = 1;
                    pk |= bv << (8 * b);
                }
                if (di < 4)       d0[di] = pk;
                else if (di < 8)  d1[di - 4] = pk;
                else if (di < 12) d2[di - 8] = pk;
                else              d3[di - 12] = pk;
            }
            v4i* dst = (v4i*)(af + (size_t)vox * 64);
            dst[0] = d0; dst[1] = d1; dst[2] = d2; dst[3] = d3;
        }
    } else {
        const int i = (bid - pb1 - af_blocks) * 256 + threadIdx.x;
        if (i < total4) {
            const int mul2 = (*mul0p) << 1;
            const int4 v = ((const int4*)x32)[i];
            int r = 0, q;
            q = __mulhi(v.x, mul2); q = q > 127 ? 127 : (q < -127 ? -127 : q); r |= (q & 0xff);
            q = __mulhi(v.y, mul2); q = q > 127 ? 127 : (q < -127 ? -127 : q); r |= (q & 0xff) << 8;
            q = __mulhi(v.z, mul2); q = q > 127 ? 127 : (q < -127 ? -127 : q); r |= (q & 0xff) << 16;
            q = __mulhi(v.w, mul2); q = q > 127 ? 127 : (q < -127 ? -127 : q); r |= (q & 0xff) << 24;
            q0[i] = r;
        }
    }
}

// k-split MFMA conv, 1 barrier/tile, software-pipelined cross-wave reduction.
//  - wave wv owns k-slices [7wv,7wv+7) for all 64 out channels; wv3's 7th slice
//    is the affine slice (precomputed af[] table)
//  - s_off [2][16][36] packed; lane reads its 7 offsets via 2x ds_read_b128
//  - DEEP PREFETCH: idx/mask of tile t+3 loaded at iter i (regs), published at
//    iter i+1; x32 of tile t loaded at iter i, used by epilogue at iter i+1.
//    Every global load now has >= 1 full iteration of latency cover.
//  - one lgkmcnt(0)+s_barrier per tile; vmem loads stay in flight across it
// REQUIRES nvox % 16 == 0 (100000 = 6250*16).
template <int LAYER>
__global__ void __launch_bounds__(256, 2)
k_conv(const int8_t* __restrict__ fin,   // [(nvox+1)*64] int8 (row nvox = zeros)
       const int* __restrict__ in_idx,   // [nvox*27]
       const int* __restrict__ mask,     // [nvox*27] (0/1)
       const int8_t* __restrict__ wext,  // [28*64*64] packed int8
       const int8_t* __restrict__ af,    // [nvox*64] affine A-rows
       const int* __restrict__ mul1,     // [64]   (layer 1)
       const int* __restrict__ slopep,   // scalar (layer 1)
       const int* __restrict__ x32,      // [nvox*64] residual (layer 2)
       int8_t* __restrict__ q1out,       // layer-1 output
       int* __restrict__ out,            // layer-2 output
       int nvox, int ntiles)
{
    __shared__ int s_off[2][16][36];          // [slot][row][wv*8+j] byte offsets
    __shared__ v4i s_red[2][4][4][64];        // [parity][writer][group][lane]

    const int tid  = threadIdx.x;
    const int lane = tid & 63;
    const int wv   = tid >> 6;
    const int arow = lane & 15;
    const int srow = lane >> 4;
    const int col  = wv * 16 + arow;

    // publish-entry mapping: entry e (row*27+slice) -> packed slot
    const int e0 = tid;            // 0..255
    const int e1 = tid + 176;      // 176..431 (dup writes benign: same values)
    const int r0 = e0 / 27, s0 = e0 - r0 * 27;
    const int r1 = e1 / 27, s1 = e1 - r1 * 27;
    const int slot0 = r0 * 36 + (s0 / 7) * 8 + (s0 % 7);
    const int slot1 = r1 * 36 + (s1 / 7) * 8 + (s1 % 7);
    int* const offl = &s_off[0][0][0];
    const int OFFSTR = 16 * 36;

    v4i wreg[7][4];
#pragma unroll
    for (int j = 0; j < 7; ++j)
#pragma unroll
        for (int g = 0; g < 4; ++g)
            wreg[j][g] = *(const v4i*)(wext +
                ((size_t)((7 * wv + j) * CCH + g * 16 + arow)) * CCH + srow * 16);

    const int mul2     = (LAYER == 1) ? (mul1[col] << 1) : 0;
    const int slope128 = (LAYER == 1) ? ((*slopep) << 7) : 0;

    const int stride = gridDim.x;
    const int t0 = blockIdx.x;
    if (t0 >= ntiles) return;
    const int cnt = (ntiles - 1 - t0) / stride + 1;

    v4i aA[7], aB[7];
    v4i accP = {0, 0, 0, 0};
    // deep-prefetch register pairs (swap each iteration)
    int pAa0, pAm0, pAa1, pAm1, pBa0, pBm0, pBa1, pBm1;
    int xA0 = 0, xA1 = 0, xA2 = 0, xA3 = 0, xB0 = 0, xB1 = 0, xB2 = 0, xB3 = 0;

#define GATHER_A(AN, SN, NB)                                                   \
    {                                                                          \
        const v4i o0_ = *(const v4i*)&s_off[SN][arow][wv * 8];                 \
        const v4i o1_ = *(const v4i*)&s_off[SN][arow][wv * 8 + 4];             \
        const int offs_[7] = {o0_[0], o0_[1], o0_[2], o0_[3],                  \
                              o1_[0], o1_[1], o1_[2]};                         \
        _Pragma("unroll")                                                      \
        for (int j = 0; j < 7; ++j) {                                          \
            if (wv == 3 && j == 6) {                                           \
                AN[6] = *(const v4i*)(af + (size_t)((NB) + arow) * CCH + srow * 16); \
            } else {                                                           \
                AN[j] = *(const v4i*)(fin + offs_[j] + srow * 16);             \
            }                                                                  \
        }                                                                      \
    }

#define EPILOGUE(TOT, NBP, X0, X1, X2, X3)                                     \
    if (LAYER == 1) {                                                          \
        int8_t* rp_ = q1out + (size_t)((NBP) + srow * 4) * CCH + col;          \
        _Pragma("unroll")                                                      \
        for (int r = 0; r < 4; ++r) {                                          \
            const int v_ = TOT[r];                                             \
            const int p_ = (v_ >= 0) ? v_ : __mulhi(v_, slope128);             \
            int q_ = __mulhi(p_, mul2);                                        \
            q_ = q_ > 127 ? 127 : (q_ < -127 ? -127 : q_);                     \
            rp_[r * CCH] = (int8_t)q_;                                         \
        }                                                                      \
    } else {                                                                   \
        int* rp_ = out + (size_t)((NBP) + srow * 4) * CCH + col;               \
        rp_[0 * CCH] = TOT[0] + X0;                                            \
        rp_[1 * CCH] = TOT[1] + X1;                                            \
        rp_[2 * CCH] = TOT[2] + X2;                                            \
        rp_[3 * CCH] = TOT[3] + X3;                                            \
    }

// PFCa0.. = regs holding idx/mask of tile t+2 (published this iter)
// PFNa0.. = regs receiving idx/mask of tile t+3 (published next iter)
// XC0..   = x32 rows of tile t-1 (used by this iter's epilogue)
// XN0..   = receives x32 rows of tile t (used next iter)
#define ITER(AC, AN, P, DO_EPI, PFCa0, PFCm0, PFCa1, PFCm1,                    \
             PFNa0, PFNm0, PFNa1, PFNm1, XC0, XC1, XC2, XC3, XN0, XN1, XN2, XN3) \
    do {                                                                       \
        /* (a) issue deep prefetches: idx/mask[t+3], x32[t] */                 \
        int tp3_ = t + 3 * stride; if (tp3_ >= ntiles) tp3_ = ntiles - 1;      \
        const size_t b3_ = (size_t)tp3_ * (16 * KK);                           \
        PFNa0 = in_idx[b3_ + e0]; PFNm0 = mask[b3_ + e0];                      \
        PFNa1 = in_idx[b3_ + e1]; PFNm1 = mask[b3_ + e1];                      \
        if (LAYER == 2) {                                                      \
            const int* xp_ = x32 + (size_t)(t * 16 + srow * 4) * CCH + col;    \
            XN0 = xp_[0 * CCH]; XN1 = xp_[1 * CCH];                            \
            XN2 = xp_[2 * CCH]; XN3 = xp_[3 * CCH];                            \
        }                                                                      \
        const int nbp_ = (t - stride) * 16;                                    \
        /* (b) issue next tile's A gathers */                                  \
        GATHER_A(AN, (P) ^ 1, (t + stride < ntiles ? (t + stride) * 16 : (ntiles - 1) * 16)) \
        __builtin_amdgcn_sched_barrier(0);                                     \
        /* (c) 28 MFMAs on AC */                                               \
        v4i acc0 = {0,0,0,0}, acc1 = {0,0,0,0}, acc2 = {0,0,0,0}, acc3 = {0,0,0,0}; \
        __builtin_amdgcn_s_setprio(1);                                         \
        _Pragma("unroll")                                                      \
        for (int j = 0; j < 7; ++j) {                                          \
            acc0 = __builtin_amdgcn_mfma_i32_16x16x64_i8(AC[j], wreg[j][0], acc0, 0, 0, 0); \
            acc1 = __builtin_amdgcn_mfma_i32_16x16x64_i8(AC[j], wreg[j][1], acc1, 0, 0, 0); \
            acc2 = __builtin_amdgcn_mfma_i32_16x16x64_i8(AC[j], wreg[j][2], acc2, 0, 0, 0); \
            acc3 = __builtin_amdgcn_mfma_i32_16x16x64_i8(AC[j], wreg[j][3], acc3, 0, 0, 0); \
        }                                                                      \
        __builtin_amdgcn_s_setprio(0);                                         \
        /* (d) write foreign partials for tile t into s_red[P] */              \
        if (wv != 0) s_red[P][wv][0][lane] = acc0;                             \
        if (wv != 1) s_red[P][wv][1][lane] = acc1;                             \
        if (wv != 2) s_red[P][wv][2][lane] = acc2;                             \
        if (wv != 3) s_red[P][wv][3][lane] = acc3;                             \
        /* (e) reduce + store tile t-1 from s_red[P^1] + accP, x32 from XC */  \
        if (DO_EPI) {                                                          \
            v4i tot = accP;                                                    \
            _Pragma("unroll")                                                  \
            for (int w = 0; w < 4; ++w) {                                      \
                if (w != wv) {                                                 \
                    const v4i r_ = s_red[(P) ^ 1][w][wv][lane];                \
                    tot[0] += r_[0]; tot[1] += r_[1];                          \
                    tot[2] += r_[2]; tot[3] += r_[3];                          \
                }                                                              \
            }                                                                  \
            EPILOGUE(tot, nbp_, XC0, XC1, XC2, XC3)                            \
        }                                                                      \
        /* (f) publish tile t+2's offsets from PFC (loaded last iteration) */  \
        offl[(P) * OFFSTR + slot0] = (PFCm0 ? PFCa0 : nvox) << 6;              \
        offl[(P) * OFFSTR + slot1] = (PFCm1 ? PFCa1 : nvox) << 6;              \
        accP = (wv == 0) ? acc0 : (wv == 1) ? acc1 : (wv == 2) ? acc2 : acc3;  \
        asm volatile("s_waitcnt lgkmcnt(0)" ::: "memory");                     \
        __builtin_amdgcn_s_barrier();                                          \
    } while (0)

    // ---- prologue: publish off[t0],off[t1]; preload pA=off-src[t0+2s]; gather aA ----
    {
        const size_t base = (size_t)t0 * (16 * KK);
        const int a0 = in_idx[base + e0], m0 = mask[base + e0];
        const int a1 = in_idx[base + e1], m1 = mask[base + e1];
        offl[0 * OFFSTR + slot0] = (m0 ? a0 : nvox) << 6;
        offl[0 * OFFSTR + slot1] = (m1 ? a1 : nvox) << 6;
    }
    int pa0, pa1, pm0, pm1;
    {
        int t1c = t0 + stride; if (t1c >= ntiles) t1c = ntiles - 1;
        const size_t base = (size_t)t1c * (16 * KK);
        pa0 = in_idx[base + e0]; pm0 = mask[base + e0];
        pa1 = in_idx[base + e1]; pm1 = mask[base + e1];
    }
    {
        int t2c = t0 + 2 * stride; if (t2c >= ntiles) t2c = ntiles - 1;
        const size_t base = (size_t)t2c * (16 * KK);
        pAa0 = in_idx[base + e0]; pAm0 = mask[base + e0];
        pAa1 = in_idx[base + e1]; pAm1 = mask[base + e1];
    }
    __syncthreads();
    GATHER_A(aA, 0, t0 * 16)
    offl[1 * OFFSTR + slot0] = (pm0 ? pa0 : nvox) << 6;
    offl[1 * OFFSTR + slot1] = (pm1 ? pa1 : nvox) << 6;
    asm volatile("s_waitcnt lgkmcnt(0)" ::: "memory");
    __builtin_amdgcn_s_barrier();

    // ---- main loop (2x unrolled: A-buf, PF pair, X pair all swap) ----
    int t = t0;
    ITER(aA, aB, 0, 0, pAa0, pAm0, pAa1, pAm1, pBa0, pBm0, pBa1, pBm1,
         xA0, xA1, xA2, xA3, xB0, xB1, xB2, xB3);
    t += stride;
    int i = 1;
    while (i < cnt) {
        ITER(aB, aA, 1, 1, pBa0, pBm0, pBa1, pBm1, pAa0, pAm0, pAa1, pAm1,
             xB0, xB1, xB2, xB3, xA0, xA1, xA2, xA3);
        ++i; t += stride; if (i >= cnt) break;
        ITER(aA, aB, 0, 1, pAa0, pAm0, pAa1, pAm1, pBa0, pBm0, pBa1, pBm1,
             xA0, xA1, xA2, xA3, xB0, xB1, xB2, xB3);
        ++i; t += stride;
    }

    // ---- drain: epilogue for the last tile (fresh x32 load; one-time) ----
    {
        const int pl = (cnt - 1) & 1;
        const int nbl = (t0 + (cnt - 1) * stride) * 16;
        int x0 = 0, x1 = 0, x2 = 0, x3 = 0;
        if (LAYER == 2) {
            const int* xp_ = x32 + (size_t)(nbl + srow * 4) * CCH + col;
            x0 = xp_[0 * CCH]; x1 = xp_[1 * CCH];
            x2 = xp_[2 * CCH]; x3 = xp_[3 * CCH];
        }
        v4i tot = accP;
#pragma unroll
        for (int w = 0; w < 4; ++w) {
            if (w != wv) {
                const v4i r_ = s_red[pl][w][wv][lane];
                tot[0] += r_[0]; tot[1] += r_[1];
                tot[2] += r_[2]; tot[3] += r_[3];
            }
        }
        EPILOGUE(tot, nbl, x0, x1, x2, x3)
    }
#undef ITER
#undef EPILOGUE
#undef GATHER_A
}

extern "C" void kernel_launch(void* const* d_in, const int* in_sizes, int n_in,
                              void* d_out, int out_size, void* d_ws, size_t ws_size,
                              hipStream_t stream) {
    // ALL integer inputs arrive as int32 on device, regardless of reference dtype.
    const int* x32    = (const int*)d_in[0];
    const int* in_idx = (const int*)d_in[1];
    const int* mask   = (const int*)d_in[2];
    const int* w1_32  = (const int*)d_in[3];
    const int* b1     = (const int*)d_in[4];
    const int* comp1  = (const int*)d_in[5];
    const int* w2_32  = (const int*)d_in[6];
    const int* b2     = (const int*)d_in[7];
    const int* comp2  = (const int*)d_in[8];
    const int* mul0   = (const int*)d_in[9];
    const int* mul1   = (const int*)d_in[10];
    const int* slope  = (const int*)d_in[11];

    const int nvox = in_sizes[0] / CCH;                 // 100000 (%16==0)
    const size_t wext_b = (size_t)28 * CCH * CCH;       // 114688 per layer
    const size_t fbytes = (size_t)(nvox + 1) * CCH;     // +1 zero row
    const size_t falign = (fbytes + 255) & ~(size_t)255;
    const size_t walign = (wext_b + 255) & ~(size_t)255;

    int8_t* q0;
    int8_t* q1;
    int8_t* w1e;
    int8_t* w2e;
    int8_t* af;
    if (ws_size >= 3 * falign + 2 * walign) {
        q0  = (int8_t*)d_ws;
        q1  = q0 + falign;
        w1e = q1 + falign;
        w2e = w1e + walign;
        af  = w2e + walign;
    } else {
        // stage q0 in d_out's bytes (dead after conv1; conv2 rewrites d_out fully)
        q0  = (int8_t*)d_out;
        q1  = (int8_t*)d_ws;
        w1e = q1 + falign;
        w2e = w1e + walign;
        af  = w2e + walign;
    }

    const int total4 = (nvox * CCH) / 4;                          // 1.6e6
    const int pb1 = (2 * WN + 8192 + 32 + 255) / 256;             // 897
    const int af_blocks  = (nvox + 255) / 256;                    // 391
    const int req_blocks = (total4 + 255) / 256;                  // 6250
    k_prep<<<pb1 + af_blocks + req_blocks, 256, 0, stream>>>(
        x32, mul0, w1_32, w2_32, comp1, b1, comp2, b2, mask,
        w1e, w2e, (int*)q0, (int*)q1, af, pb1, af_blocks, nvox, total4);

    const int ntiles = nvox / 16;                       // 6250 (exact)
    int cblocks = 512;                                  // 2 resident blocks/CU
    if (cblocks > ntiles) cblocks = ntiles;
    k_conv<1><<<cblocks, 256, 0, stream>>>(q0, in_idx, mask, w1e, af,
                                           mul1, slope, nullptr,
                                           q1, nullptr, nvox, ntiles);
    k_conv<2><<<cblocks, 256, 0, stream>>>(q1, in_idx, mask, w2e, af,
                                           nullptr, nullptr, x32,
                                           nullptr, (int*)d_out, nvox, ntiles);
}